// Round 1
// 791.619 us; speedup vs baseline: 1.2260x; 1.2260x over previous
//
#include <hip/hip_runtime.h>

typedef __attribute__((ext_vector_type(8))) __bf16 bf16x8;
typedef __attribute__((ext_vector_type(4))) float f32x4;

__device__ __forceinline__ float bf2f(unsigned short u) {
    union { unsigned u; float f; } c; c.u = ((unsigned)u) << 16; return c.f;
}
__device__ __forceinline__ unsigned short f2bf(float f) {
    union { float f; unsigned u; } c; c.f = f;
    unsigned r = c.u + 0x7fffu + ((c.u >> 16) & 1u);  // RNE
    return (unsigned short)(r >> 16);
}

#define GLD_LDS16(g, l) \
    __builtin_amdgcn_global_load_lds( \
        (const __attribute__((address_space(1))) void*)(g), \
        (__attribute__((address_space(3))) void*)(l), 16, 0, 0)

// fp32 -> bf16 convert, up to 4 arrays selected by blockIdx.z, each 4096*4096.
__global__ void __launch_bounds__(256) cvt_f32_bf16(
    const float* __restrict__ s0, unsigned short* __restrict__ d0,
    const float* __restrict__ s1, unsigned short* __restrict__ d1,
    const float* __restrict__ s2, unsigned short* __restrict__ d2,
    const float* __restrict__ s3, unsigned short* __restrict__ d3)
{
    const float* s; unsigned short* d;
    if (blockIdx.z == 0)      { s = s0; d = d0; }
    else if (blockIdx.z == 1) { s = s1; d = d1; }
    else if (blockIdx.z == 2) { s = s2; d = d2; }
    else                      { s = s3; d = d3; }
    const size_t N = (size_t)4096 * 4096;
    const size_t stride = (size_t)gridDim.x * 256 * 4;
    for (size_t i = ((size_t)blockIdx.x * 256 + threadIdx.x) * 4; i < N; i += stride) {
        float4 v = *(const float4*)(s + i);
        ushort4 o;
        o.x = f2bf(v.x); o.y = f2bf(v.y); o.z = f2bf(v.z); o.w = f2bf(v.w);
        *(ushort4*)(d + i) = o;
    }
}

// ---------------------------------------------------------------------------
// 256x256-tile 8-phase GEMM (m201 template): C[m][n] = sum_k A[m][k]*W[n][k]+b[n]
// A,W bf16 4096x4096 row-major. 512 threads = 8 waves (2 M x 4 N), BK=64.
// LDS 128 KiB dynamic: [buf][A 32K | B 32K], each tile = 2 halves of 128 rows,
// halves subtiled st_16x32 with XOR-bit5-by-bit9 swizzle (T2). Counted vmcnt
// (T4), raw s_barrier phases (T3), setprio around MFMA clusters (T5).
// grid=(16,16,z): z picks (W,bias,C) triple.
// ---------------------------------------------------------------------------
template <bool OUTF32>
__global__ void __launch_bounds__(512, 2) gemm256(
    const unsigned short* __restrict__ A,
    const unsigned short* __restrict__ W0, const float* __restrict__ b0, void* __restrict__ C0,
    const unsigned short* __restrict__ W1, const float* __restrict__ b1, void* __restrict__ C1,
    const unsigned short* __restrict__ W2, const float* __restrict__ b2, void* __restrict__ C2)
{
    constexpr int K = 4096;
    constexpr int NT = 64;          // K / BK
    extern __shared__ char smem[];  // 131072 B

    const unsigned short* W; const float* bias; void* C;
    if (blockIdx.z == 0)      { W = W0; bias = b0; C = C0; }
    else if (blockIdx.z == 1) { W = W1; bias = b1; C = C1; }
    else                      { W = W2; bias = b2; C = C2; }

    const int tid  = threadIdx.x;
    const int lane = tid & 63;
    const int wave = tid >> 6;
    const int wm = wave >> 2;       // 0..1 -> rows wm*128..+127
    const int wn = wave & 3;        // 0..3 -> cols wn*64..+63
    const int m0 = blockIdx.y * 256;
    const int n0 = blockIdx.x * 256;

    // ---- staging address decode (rule #21: linear LDS dest, inverse-swizzled
    // global source). Physical byte p = tid*16 within a 16KB half-region.
    const int p = tid << 4;
    const int o = p ^ (((p >> 9) & 1) << 5);                 // logical offset
    const int srow = ((o >> 11) << 4) | ((o >> 6) & 15);     // 0..63
    const int scol = (((o >> 10) & 1) << 5) | ((o & 63) >> 1);
    const unsigned short* pA = A + (size_t)(m0 + srow) * K + scol;
    const unsigned short* pB = W + (size_t)(n0 + srow) * K + scol;

    // ---- fragment-read offsets (swizzled). lane holds row=..+fl, k=kk*32+qg*8
    const int fl = lane & 15;
    const int qg = lane >> 4;
    int rdoff = (fl << 6) + (qg << 4);
    rdoff ^= (fl & 8) << 2;                                  // st_16x32 swizzle
    // A: + buf*65536 + mh*8192 + it*2048 + kk*1024
    const int aOffc = (wm << 14) + rdoff;
    // B: + buf*65536 + nh*4096 + jt*2048 + kk*1024
    const int bOffc = 32768 + ((wn >> 1) << 14) + ((wn & 1) << 13) + rdoff;

    f32x4 acc[8][4];
#pragma unroll
    for (int i = 0; i < 8; i++)
#pragma unroll
        for (int j = 0; j < 4; j++) acc[i][j] = (f32x4){0.f, 0.f, 0.f, 0.f};

    bf16x8 af[4][2], bfr0[2][2], bfr1[2][2];

#define STAGE_A(tt, h, bb) do { \
    GLD_LDS16(pA + (size_t)(tt) * 64 + (size_t)(h) * 524288, \
              smem + (bb) * 65536 + (h) * 16384 + (wave << 10)); \
    GLD_LDS16(pA + (size_t)(tt) * 64 + (size_t)(h) * 524288 + 262144, \
              smem + (bb) * 65536 + (h) * 16384 + 8192 + (wave << 10)); \
} while (0)
#define STAGE_B(tt, h, bb) do { \
    GLD_LDS16(pB + (size_t)(tt) * 64 + (size_t)(h) * 524288, \
              smem + (bb) * 65536 + 32768 + (h) * 16384 + (wave << 10)); \
    GLD_LDS16(pB + (size_t)(tt) * 64 + (size_t)(h) * 524288 + 262144, \
              smem + (bb) * 65536 + 32768 + (h) * 16384 + 8192 + (wave << 10)); \
} while (0)

#define RD_A(mh, bb) do { \
    _Pragma("unroll") for (int it_ = 0; it_ < 4; ++it_) \
    _Pragma("unroll") for (int kk_ = 0; kk_ < 2; ++kk_) \
        af[it_][kk_] = *(const bf16x8*)(smem + (bb) * 65536 + aOffc + (mh) * 8192 + it_ * 2048 + kk_ * 1024); \
} while (0)
#define RD_B(nh, dst, bb) do { \
    _Pragma("unroll") for (int jt_ = 0; jt_ < 2; ++jt_) \
    _Pragma("unroll") for (int kk_ = 0; kk_ < 2; ++kk_) \
        dst[jt_][kk_] = *(const bf16x8*)(smem + (bb) * 65536 + bOffc + (nh) * 4096 + jt_ * 2048 + kk_ * 1024); \
} while (0)

#define MM(mh, nh, bset) do { \
    __builtin_amdgcn_s_setprio(1); \
    _Pragma("unroll") for (int it_ = 0; it_ < 4; ++it_) \
    _Pragma("unroll") for (int jt_ = 0; jt_ < 2; ++jt_) \
    _Pragma("unroll") for (int kk_ = 0; kk_ < 2; ++kk_) \
        acc[(mh) * 4 + it_][(nh) * 2 + jt_] = __builtin_amdgcn_mfma_f32_16x16x32_bf16( \
            af[it_][kk_], bset[jt_][kk_], acc[(mh) * 4 + it_][(nh) * 2 + jt_], 0, 0, 0); \
    __builtin_amdgcn_s_setprio(0); \
} while (0)

#define BAR() __builtin_amdgcn_s_barrier()

    // ---- prologue: tile0 fully -> buf0; tile1 B-halves -> buf1.  12 loads;
    // vmcnt(4) completes tile0, leaves tile1's B (4) in flight.
    STAGE_A(0, 0, 0); STAGE_A(0, 1, 0);
    STAGE_B(0, 0, 0); STAGE_B(0, 1, 0);
    STAGE_B(1, 0, 1); STAGE_B(1, 1, 1);
    asm volatile("s_waitcnt vmcnt(4)" ::: "memory");
    BAR();
    __builtin_amdgcn_sched_barrier(0);

    // ---- main loop. Iteration t (buffer bb = t&1), 4 phases:
    //  ph0: rd A[mh0]+B[nh0] | stage A(t+1)h0->nxt | MFMA Q(0,0)
    //  ph1: rd B[nh1]        | stage A(t+1)h1->nxt | MFMA Q(0,1)
    //  ph2: rd A[mh1]        | stage B(t+2)h0->cur | MFMA Q(1,0)
    //  ph3:                  | stage B(t+2)h1->cur | MFMA Q(1,1); vmcnt(4); bar
    // vmcnt(4) leaves only the 4 B(t+2) loads outstanding -> tile t+1 complete.
#define TILE(t, bb) do { \
    RD_A(0, bb); RD_B(0, bfr0, bb); \
    if ((t) + 1 < NT) STAGE_A((t) + 1, 0, (bb) ^ 1); \
    BAR(); MM(0, 0, bfr0); BAR(); \
    RD_B(1, bfr1, bb); \
    if ((t) + 1 < NT) STAGE_A((t) + 1, 1, (bb) ^ 1); \
    BAR(); MM(0, 1, bfr1); BAR(); \
    RD_A(1, bb); \
    if ((t) + 2 < NT) STAGE_B((t) + 2, 0, (bb)); \
    BAR(); MM(1, 0, bfr0); BAR(); \
    if ((t) + 2 < NT) STAGE_B((t) + 2, 1, (bb)); \
    BAR(); MM(1, 1, bfr1); \
    if ((t) + 2 < NT) { asm volatile("s_waitcnt vmcnt(4)" ::: "memory"); } \
    else              { asm volatile("s_waitcnt vmcnt(0)" ::: "memory"); } \
    BAR(); \
    __builtin_amdgcn_sched_barrier(0); \
} while (0)

    for (int t = 0; t < NT; t += 2) {
        TILE(t, 0);
        TILE(t + 1, 1);
    }

    // ---- epilogue. C/D layout: col = lane&15, row = (lane>>4)*4 + r [m89/m91]
    const int r0 = (lane >> 4) << 2;
#pragma unroll
    for (int j = 0; j < 4; ++j) {
        const int col = n0 + wn * 64 + j * 16 + fl;
        const float bj = bias[col];
#pragma unroll
        for (int i = 0; i < 8; ++i) {
            const int row = m0 + wm * 128 + i * 16 + r0;
#pragma unroll
            for (int r = 0; r < 4; ++r) {
                const float val = acc[i][j][r] + bj;
                if constexpr (OUTF32)
                    ((float*)C)[(size_t)(row + r) * 4096 + col] = val;
                else
                    ((unsigned short*)C)[(size_t)(row + r) * 4096 + col] = f2bf(val);
            }
        }
    }
#undef TILE
#undef BAR
#undef MM
#undef RD_B
#undef RD_A
#undef STAGE_B
#undef STAGE_A
}

// MFMA per-token attention over the HEAD axis.
// Wave w of block handles token = blockIdx.x*4 + w (fully wave-private; no barriers).
// S = Q K^T (64x64x64), softmax rows over e, O = P V^T, O -> merged layout.
__global__ void __launch_bounds__(256) attn_mfma(
    const unsigned short* __restrict__ q, const unsigned short* __restrict__ k,
    const unsigned short* __restrict__ v, unsigned short* __restrict__ merged)
{
    // per-wave P buffer: 64 rows x 72 shorts (pad 8 -> 2-way banks, 16B-aligned)
    __shared__ __align__(16) unsigned short sP[4][64 * 72];  // 36.9 KB

    const int tid  = threadIdx.x;
    const int wave = tid >> 6;
    const int lane = tid & 63;
    const int token = blockIdx.x * 4 + wave;
    const int b = token >> 6, s = token & 63;
    const size_t base = (size_t)token * 4096;

    const int fl = lane & 15;   // m/n index within a 16-tile
    const int qg = lane >> 4;   // quad group: k-chunk qg*8, acc rows qg*4..+3

    // ---- S = Q K^T : A-frags from q rows, B-frags from k rows, direct global
    f32x4 S[4][4];
#pragma unroll
    for (int i = 0; i < 4; i++)
#pragma unroll
        for (int j = 0; j < 4; j++) S[i][j] = (f32x4){0.f, 0.f, 0.f, 0.f};

#pragma unroll
    for (int ks = 0; ks < 2; ks++) {
        bf16x8 aq[4], bk[4];
#pragma unroll
        for (int t = 0; t < 4; t++) {
            aq[t] = *(const bf16x8*)(q + base + (size_t)(t * 16 + fl) * 64 + ks * 32 + qg * 8);
            bk[t] = *(const bf16x8*)(k + base + (size_t)(t * 16 + fl) * 64 + ks * 32 + qg * 8);
        }
#pragma unroll
        for (int i = 0; i < 4; i++)
#pragma unroll
            for (int j = 0; j < 4; j++)
                S[i][j] = __builtin_amdgcn_mfma_f32_16x16x32_bf16(aq[i], bk[j], S[i][j], 0, 0, 0);
    }

    // ---- softmax over e (cols). Row of S[i][j][r] = i*16 + qg*4 + r; col = j*16+fl.
    float mrow[4][4];
#pragma unroll
    for (int i = 0; i < 4; i++)
#pragma unroll
        for (int r = 0; r < 4; r++) {
            float m = S[i][0][r];
            m = fmaxf(m, S[i][1][r]); m = fmaxf(m, S[i][2][r]); m = fmaxf(m, S[i][3][r]);
            mrow[i][r] = m;
        }
#pragma unroll
    for (int off = 1; off <= 8; off <<= 1)
#pragma unroll
        for (int i = 0; i < 4; i++)
#pragma unroll
            for (int r = 0; r < 4; r++)
                mrow[i][r] = fmaxf(mrow[i][r], __shfl_xor(mrow[i][r], off));

    float lrow[4][4];
#pragma unroll
    for (int i = 0; i < 4; i++)
#pragma unroll
        for (int r = 0; r < 4; r++) lrow[i][r] = 0.f;
#pragma unroll
    for (int i = 0; i < 4; i++)
#pragma unroll
        for (int j = 0; j < 4; j++)
#pragma unroll
            for (int r = 0; r < 4; r++) {
                const float p = __expf((S[i][j][r] - mrow[i][r]) * 0.125f);
                S[i][j][r] = p;
                lrow[i][r] += p;
            }
#pragma unroll
    for (int off = 1; off <= 8; off <<= 1)
#pragma unroll
        for (int i = 0; i < 4; i++)
#pragma unroll
            for (int r = 0; r < 4; r++)
                lrow[i][r] += __shfl_xor(lrow[i][r], off);

    // ---- normalized P -> wave-private LDS (bf16), C-layout scatter
    unsigned short* myP = &sP[wave][0];
#pragma unroll
    for (int i = 0; i < 4; i++)
#pragma unroll
        for (int r = 0; r < 4; r++) {
            const float inv = 1.f / lrow[i][r];
            const int row = i * 16 + qg * 4 + r;
#pragma unroll
            for (int j = 0; j < 4; j++)
                myP[row * 72 + j * 16 + fl] = f2bf(S[i][j][r] * inv);
        }

    // ---- O = P V^T : A-frags of P from LDS, B-frags of V from global
    f32x4 O[4][4];
#pragma unroll
    for (int i = 0; i < 4; i++)
#pragma unroll
        for (int j = 0; j < 4; j++) O[i][j] = (f32x4){0.f, 0.f, 0.f, 0.f};

#pragma unroll
    for (int ks = 0; ks < 2; ks++) {
        bf16x8 ap[4], bv[4];
#pragma unroll
        for (int t = 0; t < 4; t++) {
            ap[t] = *(const bf16x8*)(myP + (t * 16 + fl) * 72 + ks * 32 + qg * 8);
            bv[t] = *(const bf16x8*)(v + base + (size_t)(t * 16 + fl) * 64 + ks * 32 + qg * 8);
        }
#pragma unroll
        for (int i = 0; i < 4; i++)
#pragma unroll
            for (int j = 0; j < 4; j++)
                O[i][j] = __builtin_amdgcn_mfma_f32_16x16x32_bf16(ap[i], bv[j], O[i][j], 0, 0, 0);
    }

    // ---- merged[(b*64 + row)][(s*64 + col)], row = i*16+qg*4+r, col = j*16+fl
#pragma unroll
    for (int i = 0; i < 4; i++)
#pragma unroll
        for (int r = 0; r < 4; r++) {
            const size_t rowbase = (size_t)(b * 64 + i * 16 + qg * 4 + r) * 4096 + s * 64;
#pragma unroll
            for (int j = 0; j < 4; j++)
                merged[rowbase + j * 16 + fl] = f2bf(O[i][j][r]);
        }
}

extern "C" void kernel_launch(void* const* d_in, const int* in_sizes, int n_in,
                              void* d_out, int out_size, void* d_ws, size_t ws_size,
                              hipStream_t stream)
{
    // inputs are FP32 per the reference
    const float* x  = (const float*)d_in[0];
    const float* Wq = (const float*)d_in[1];
    const float* bq = (const float*)d_in[2];
    const float* Wk = (const float*)d_in[3];
    const float* bk = (const float*)d_in[4];
    const float* Wv = (const float*)d_in[5];
    const float* bv = (const float*)d_in[6];
    const float* Wp = (const float*)d_in[7];
    const float* bp = (const float*)d_in[8];
    float* out = (float*)d_out;

    const size_t MAT = (size_t)4096 * 4096;  // elements per bf16 slot (32 MB)
    unsigned short* sw = (unsigned short*)d_ws;
    unsigned short* xb     = sw + 0 * MAT;   // slot0: xb, later merged
    unsigned short* Wqb    = sw + 1 * MAT;   // slot1: Wqb, later Wpb
    unsigned short* Wkb    = sw + 2 * MAT;
    unsigned short* Wvb    = sw + 3 * MAT;
    unsigned short* q      = sw + 4 * MAT;
    unsigned short* k      = sw + 5 * MAT;
    unsigned short* v      = sw + 6 * MAT;   // total 7 slots = 235 MB
    unsigned short* merged = xb;             // x dead after QKV GEMM
    unsigned short* Wpb    = Wqb;            // Wq dead after QKV GEMM

    // one-time: allow 128 KiB dynamic LDS for the 256^2 GEMM
    static bool attr_done = false;
    if (!attr_done) {
        hipFuncSetAttribute(reinterpret_cast<const void*>(gemm256<false>),
                            hipFuncAttributeMaxDynamicSharedMemorySize, 131072);
        hipFuncSetAttribute(reinterpret_cast<const void*>(gemm256<true>),
                            hipFuncAttributeMaxDynamicSharedMemorySize, 131072);
        attr_done = true;
    }

    // 1. convert x, Wq, Wk, Wv to bf16
    cvt_f32_bf16<<<dim3(2048, 1, 4), 256, 0, stream>>>(x, xb, Wq, Wqb, Wk, Wkb, Wv, Wvb);
    // 2. QKV projections (fused, 256^2-tile 8-phase)
    gemm256<false><<<dim3(16, 16, 3), 512, 131072, stream>>>(
        xb, Wqb, bq, q, Wkb, bk, k, Wvb, bv, v);
    // 3. convert Wp into slot1 (Wq dead now)
    cvt_f32_bf16<<<dim3(2048, 1, 1), 256, 0, stream>>>(Wp, Wpb, Wp, Wpb, Wp, Wpb, Wp, Wpb);
    // 4. MFMA per-token head-axis attention -> merged (slot0)
    attn_mfma<<<dim3(1024), 256, 0, stream>>>(q, k, v, merged);
    // 5. output projection -> fp32 d_out
    gemm256<true><<<dim3(16, 16, 1), 512, 131072, stream>>>(
        merged, Wpb, bp, out, Wpb, bp, out, Wpb, bp, out);
}